// Round 1
// baseline (538.122 us; speedup 1.0000x reference)
//
#include <hip/hip_runtime.h>
#include <stdint.h>

// CONV-KNRM fused pipeline for MI355X (gfx950).
// B=32, Q=16, D=4096, V=30000, C=128, EM=300, NBINS=11.
//
// Stage A: P[v][0:768] = wv[v] @ [Wu0 | Wb0 | Wb1 | Wt0 | Wt1 | Wt2]^T  (bf16, MFMA)
// Stage B: per (b, type, pos): vec = l2norm(relu(sum_j P[tok_{l+j}][seg_j] + bias)+1e-9)
//          stored bf16 + inv-norm-after-rounding (keeps exact-match sims == 1).
// Stage C: fused sim (MFMA 16x16x32 bf16) + 11 Gaussian bins + doc-sum into
//          global accumulator [32][3 qt][16][3 dt][11] via quad-reduce + atomicAdd.
// Stage D: out[b][pool*11+bin] = sum_q 0.01*log(max(acc,1e-10)).

typedef short short8 __attribute__((ext_vector_type(8)));
typedef float floatx4 __attribute__((ext_vector_type(4)));

#define NB_V 30000

__device__ __forceinline__ unsigned short f32_bf16(float f) {
  union { float f; uint32_t u; } v; v.f = f;
  return (unsigned short)((v.u + 0x7FFFu + ((v.u >> 16) & 1u)) >> 16);
}
__device__ __forceinline__ float bf16_f32(unsigned short h) {
  union { uint32_t u; float f; } v; v.u = ((uint32_t)h) << 16;
  return v.f;
}

// ---------------- zero the pooling accumulator ----------------
__global__ void k_zero(float* __restrict__ g, int n) {
  int i = blockIdx.x * 256 + threadIdx.x;
  if (i < n) g[i] = 0.0f;
}

// ---------------- Stage A: vocab projection GEMM ----------------
// grid = 235 Mblocks x 12 Nblocks; block 256 (4 waves).
// Nblock = 64 cols; segment s=nb>>1 selects (Wsrc, j); K=300 padded to 320.
__global__ __launch_bounds__(256) void k_project(
    const float* __restrict__ wv,
    const float* __restrict__ Wu, const float* __restrict__ Wb,
    const float* __restrict__ Wt,
    unsigned short* __restrict__ P) {
  __shared__ __align__(16) unsigned short wlds[64 * 328];  // stride 328: 2-way-free banks
  int tid = threadIdx.x;
  int bid = blockIdx.x;
  int mb = bid / 12, nb = bid % 12;
  int seg = nb >> 1, h = nb & 1;
  const float* Wsrc; int kw, jj;
  if (seg == 0)       { Wsrc = Wu; kw = 1; jj = 0; }
  else if (seg <= 2)  { Wsrc = Wb; kw = 2; jj = seg - 1; }
  else                { Wsrc = Wt; kw = 3; jj = seg - 3; }
  {
    int cl = tid >> 2;                 // 0..63 local col
    int k0 = (tid & 3) * 80;
    const float* srow = Wsrc + ((size_t)(h * 64 + cl) * kw + jj) * 300;
    unsigned short* drow = &wlds[cl * 328];
    for (int i = 0; i < 20; i++) {
      int k = k0 + i * 4;
      float x0 = 0.f, x1 = 0.f, x2 = 0.f, x3 = 0.f;
      if (k + 4 <= 300) {
        float4 f = *(const float4*)(srow + k);
        x0 = f.x; x1 = f.y; x2 = f.z; x3 = f.w;
      }
      drow[k + 0] = f32_bf16(x0); drow[k + 1] = f32_bf16(x1);
      drow[k + 2] = f32_bf16(x2); drow[k + 3] = f32_bf16(x3);
    }
  }
  __syncthreads();

  int wave = tid >> 6, lane = tid & 63;
  int li = lane & 15, quad = lane >> 4;
  int rows0 = mb * 128 + wave * 32;
  floatx4 acc[2][4];
#pragma unroll
  for (int rt = 0; rt < 2; rt++)
#pragma unroll
    for (int ct = 0; ct < 4; ct++) acc[rt][ct] = (floatx4){0.f, 0.f, 0.f, 0.f};

  for (int ks = 0; ks < 10; ks++) {
    int ck = ks * 32 + quad * 8;
    short8 af[2];
#pragma unroll
    for (int rt = 0; rt < 2; rt++) {
      int row = rows0 + rt * 16 + li;
      float f[8];
      if (row < NB_V && ck + 8 <= 300) {
        const float* p = wv + (size_t)row * 300 + ck;
        float4 a = *(const float4*)p;
        float4 b2 = *(const float4*)(p + 4);
        f[0]=a.x; f[1]=a.y; f[2]=a.z; f[3]=a.w;
        f[4]=b2.x; f[5]=b2.y; f[6]=b2.z; f[7]=b2.w;
      } else if (row < NB_V) {
#pragma unroll
        for (int e = 0; e < 8; e++)
          f[e] = (ck + e < 300) ? wv[(size_t)row * 300 + ck + e] : 0.f;
      } else {
#pragma unroll
        for (int e = 0; e < 8; e++) f[e] = 0.f;
      }
      short8 t;
#pragma unroll
      for (int e = 0; e < 8; e++) t[e] = (short)f32_bf16(f[e]);
      af[rt] = t;
    }
#pragma unroll
    for (int ct = 0; ct < 4; ct++) {
      short8 bf = *(const short8*)&wlds[(ct * 16 + li) * 328 + ck];
      acc[0][ct] = __builtin_amdgcn_mfma_f32_16x16x32_bf16(af[0], bf, acc[0][ct], 0, 0, 0);
      acc[1][ct] = __builtin_amdgcn_mfma_f32_16x16x32_bf16(af[1], bf, acc[1][ct], 0, 0, 0);
    }
  }
#pragma unroll
  for (int rt = 0; rt < 2; rt++)
#pragma unroll
    for (int ct = 0; ct < 4; ct++)
#pragma unroll
      for (int r = 0; r < 4; r++) {
        int row = rows0 + rt * 16 + quad * 4 + r;
        if (row < NB_V)
          P[(size_t)row * 768 + nb * 64 + ct * 16 + li] = f32_bf16(acc[rt][ct][r]);
      }
}

// ---------------- Stage B: build normalized n-gram vectors ----------------
__device__ __forceinline__ void build_vec(
    int b, int type, int l, int L,
    const int* __restrict__ tokens, const unsigned short* __restrict__ P,
    const float* __restrict__ bias,
    unsigned short* __restrict__ vec, float* __restrict__ inv, int lane) {
  const int segBase[3] = {0, 128, 384};
  size_t row = (size_t)(b * 3 + type) * L + l;
  uint32_t* vout = (uint32_t*)(vec + row * 128);
  int kk = type + 1;
  if (l + kk <= L) {
    const int* tk = tokens + (size_t)b * L + l;
    float v0 = bias[2 * lane], v1 = bias[2 * lane + 1];
    for (int j = 0; j < kk; j++) {
      uint32_t pp = *(const uint32_t*)(P + (size_t)tk[j] * 768 + segBase[type] + j * 128 + 2 * lane);
      v0 += bf16_f32((unsigned short)(pp & 0xFFFFu));
      v1 += bf16_f32((unsigned short)(pp >> 16));
    }
    v0 = fmaxf(v0, 0.0f) + 1e-9f;
    v1 = fmaxf(v1, 0.0f) + 1e-9f;
    float ss = v0 * v0 + v1 * v1;
#pragma unroll
    for (int o = 1; o < 64; o <<= 1) ss += __shfl_xor(ss, o);
    float rn = 1.0f / sqrtf(ss);
    unsigned short r0 = f32_bf16(v0 * rn), r1 = f32_bf16(v1 * rn);
    float f0 = bf16_f32(r0), f1 = bf16_f32(r1);
    float s2 = f0 * f0 + f1 * f1;
#pragma unroll
    for (int o = 1; o < 64; o <<= 1) s2 += __shfl_xor(s2, o);
    vout[lane] = (uint32_t)r0 | ((uint32_t)r1 << 16);
    if (lane == 0) inv[row] = rsqrtf(s2);   // 1/||bf16 vec||: exact-match sims -> 1.0
  } else {
    vout[lane] = 0u;
    if (lane == 0) inv[row] = 0.0f;
  }
}

__global__ __launch_bounds__(256) void k_vectors(
    const int* __restrict__ qtok, const int* __restrict__ dtok,
    const unsigned short* __restrict__ P,
    const float* __restrict__ bu, const float* __restrict__ bb,
    const float* __restrict__ bt,
    unsigned short* __restrict__ dvec, float* __restrict__ dinv,
    unsigned short* __restrict__ qvec, float* __restrict__ qinv) {
  int wid = blockIdx.x * 4 + (threadIdx.x >> 6);
  int lane = threadIdx.x & 63;
  const int NDOCW = 32 * 3 * 1024;  // doc waves, 4 positions each
  if (wid < NDOCW) {
    int b = wid / 3072;
    int rem = wid % 3072;
    int type = rem / 1024;
    int l0 = (rem % 1024) * 4;
    const float* bias = (type == 0) ? bu : (type == 1) ? bb : bt;
    for (int pi = 0; pi < 4; pi++)
      build_vec(b, type, l0 + pi, 4096, dtok, P, bias, dvec, dinv, lane);
  } else {
    int t2 = wid - NDOCW;
    if (t2 < 32 * 48) {
      int b = t2 / 48;
      int rem = t2 % 48;
      int type = rem >> 4, l = rem & 15;
      const float* bias = (type == 0) ? bu : (type == 1) ? bb : bt;
      build_vec(b, type, l, 16, qtok, P, bias, qvec, qinv, lane);
    }
  }
}

// ---------------- Stage C: fused sim + Gaussian kernel pooling ----------------
// grid = 32 batches * 3 dtypes * 16 chunks (256 docs/chunk). block 256 = 4 waves.
__global__ __launch_bounds__(256) void k_pool(
    const unsigned short* __restrict__ dvec, const float* __restrict__ dinv,
    const unsigned short* __restrict__ qvec, const float* __restrict__ qinv,
    float* __restrict__ gacc) {
  constexpr float MU[11] = {1.f, .9f, .7f, .5f, .3f, .1f, -.1f, -.3f, -.5f, -.7f, -.9f};
  constexpr float CF[11] = {-500000.f, -50.f, -50.f, -50.f, -50.f, -50.f,
                            -50.f, -50.f, -50.f, -50.f, -50.f};
  __shared__ __align__(16) unsigned short qlds[48 * 136];  // +8 pad: 2-way-free banks
  __shared__ float qil[48];
  int bid = blockIdx.x;
  int b = bid / 48, rem = bid % 48;
  int dt = rem / 16, chunk = rem % 16;
  int tid = threadIdx.x;
  for (int idx = tid; idx < 48 * 32; idx += 256) {
    int row = idx >> 5, kq = (idx & 31) * 4;
    *(uint2*)&qlds[row * 136 + kq] =
        *(const uint2*)(qvec + ((size_t)b * 48 + row) * 128 + kq);
  }
  if (tid < 48) qil[tid] = qinv[b * 48 + tid];
  __syncthreads();

  int wave = tid >> 6, lane = tid & 63;
  int li = lane & 15, quad = lane >> 4;
  int validD = 4096 - dt;
  const unsigned short* dbp = dvec + ((size_t)b * 3 + dt) * 4096 * 128;
  const float* dip = dinv + ((size_t)b * 3 + dt) * 4096;

  float accb[3][11];
#pragma unroll
  for (int qt = 0; qt < 3; qt++)
#pragma unroll
    for (int i = 0; i < 11; i++) accb[qt][i] = 0.f;

  for (int blk = wave; blk < 16; blk += 4) {
    int db = chunk * 256 + blk * 16;
    const short8* ap = (const short8*)(dbp + (size_t)(db + li) * 128 + quad * 8);
    short8 af0 = ap[0], af1 = ap[4], af2 = ap[8], af3 = ap[12];
    float4 iv4 = *(const float4*)(dip + db + quad * 4);
    float iv[4] = {iv4.x, iv4.y, iv4.z, iv4.w};
#pragma unroll
    for (int qt = 0; qt < 3; qt++) {
      floatx4 sim = (floatx4){0.f, 0.f, 0.f, 0.f};
      const unsigned short* qb = &qlds[(qt * 16 + li) * 136 + quad * 8];
      sim = __builtin_amdgcn_mfma_f32_16x16x32_bf16(af0, *(const short8*)(qb), sim, 0, 0, 0);
      sim = __builtin_amdgcn_mfma_f32_16x16x32_bf16(af1, *(const short8*)(qb + 32), sim, 0, 0, 0);
      sim = __builtin_amdgcn_mfma_f32_16x16x32_bf16(af2, *(const short8*)(qb + 64), sim, 0, 0, 0);
      sim = __builtin_amdgcn_mfma_f32_16x16x32_bf16(af3, *(const short8*)(qb + 96), sim, 0, 0, 0);
      float invq = qil[qt * 16 + li];
#pragma unroll
      for (int r = 0; r < 4; r++) {
        if (db + quad * 4 + r < validD) {
          float s = sim[r] * (invq * iv[r]);
#pragma unroll
          for (int i = 0; i < 11; i++) {
            float t = s - MU[i];
            accb[qt][i] += __expf(t * t * CF[i]);
          }
        }
      }
    }
  }
#pragma unroll
  for (int qt = 0; qt < 3; qt++) {
#pragma unroll
    for (int i = 0; i < 11; i++) {
      float v = accb[qt][i];
      v += __shfl_xor(v, 16);
      v += __shfl_xor(v, 32);
      if (lane < 16 - qt)   // lane == qrow here; masks padded q rows too
        atomicAdd(&gacc[(((size_t)b * 3 + qt) * 16 + lane) * 33 + dt * 11 + i], v);
    }
  }
}

// ---------------- Stage D: log / clip / query-sum epilogue ----------------
__global__ void k_final(const float* __restrict__ gacc, float* __restrict__ out) {
  int idx = blockIdx.x * 256 + threadIdx.x;
  if (idx >= 32 * 99) return;
  int b = idx / 99, r = idx % 99;
  int p = r / 11, bin = r % 11;
  const int qt_of[9] = {0, 0, 0, 1, 2, 1, 1, 2, 2};
  const int dt_of[9] = {0, 2, 1, 0, 0, 1, 2, 1, 2};
  int qt = qt_of[p], dt = dt_of[p];
  float s = 0.f;
  for (int q = 0; q < 16 - qt; q++) {
    float v = gacc[((b * 3 + qt) * 16 + q) * 33 + dt * 11 + bin];
    s += 0.01f * logf(fmaxf(v, 1e-10f));
  }
  out[idx] = s;
}

extern "C" void kernel_launch(void* const* d_in, const int* in_sizes, int n_in,
                              void* d_out, int out_size, void* d_ws, size_t ws_size,
                              hipStream_t stream) {
  const int* qtok = (const int*)d_in[0];
  const int* dtok = (const int*)d_in[1];
  // d_in[2] = batch_semantic: unused by the reference
  const float* wv = (const float*)d_in[3];
  const float* Wu = (const float*)d_in[4];
  const float* bu = (const float*)d_in[5];
  const float* Wb = (const float*)d_in[6];
  const float* bb = (const float*)d_in[7];
  const float* Wt = (const float*)d_in[8];
  const float* bt = (const float*)d_in[9];
  float* out = (float*)d_out;

  // workspace layout (all 16B aligned), total 148,918,272 B
  char* ws = (char*)d_ws;
  unsigned short* P    = (unsigned short*)(ws);               // 30000*768*2      = 46,080,000
  unsigned short* dvec = (unsigned short*)(ws + 46080000);    // 32*3*4096*128*2  = 100,663,296
  float* dinv          = (float*)(ws + 146743296);            // 32*3*4096*4      = 1,572,864
  unsigned short* qvec = (unsigned short*)(ws + 148316160);   // 32*3*16*128*2    = 393,216
  float* qinv          = (float*)(ws + 148709376);            // 32*3*16*4        = 6,144
  float* gacc          = (float*)(ws + 148715520);            // 32*3*16*33*4     = 202,752

  k_zero<<<198, 256, 0, stream>>>(gacc, 50688);
  k_project<<<235 * 12, 256, 0, stream>>>(wv, Wu, Wb, Wt, P);
  k_vectors<<<24960, 256, 0, stream>>>(qtok, dtok, P, bu, bb, bt, dvec, dinv, qvec, qinv);
  k_pool<<<32 * 3 * 16, 256, 0, stream>>>(dvec, dinv, qvec, qinv, gacc);
  k_final<<<13, 256, 0, stream>>>(gacc, out);
}

// Round 2
// 332.238 us; speedup vs baseline: 1.6197x; 1.6197x over previous
//
#include <hip/hip_runtime.h>
#include <stdint.h>

// CONV-KNRM fused pipeline for MI355X (gfx950). Round 2: no global atomics.
// B=32, Q=16, D=4096, V=30000, C=128, EM=300, NBINS=11.
//
// k_convert: wv (30000x300 f32) -> wv_bf (30080x320 bf16, zero-padded)
// k_project: P[v][0:768] = wv_bf[v] @ [Wu0|Wb0|Wb1|Wt0|Wt1|Wt2]^T (MFMA bf16)
// k_vectors: per (b,type,pos): vec = l2norm(relu(sum_j P[tok][seg_j]+bias)+1e-9)
//            stored bf16 + inv-norm-after-rounding (exact-match sims == 1).
// k_pool:    fused sim MFMA + 11 Gaussian bins; block-local LDS reduction ->
//            per-block partial[bid][528] plain stores (NO atomics).
// k_reduce:  sum 16 chunks -> gacc[32][3qt][16][3dt][11]
// k_final:   out[b][pool*11+bin] = sum_q 0.01*log(max(acc,1e-10))

typedef short short8 __attribute__((ext_vector_type(8)));
typedef unsigned short ushort8 __attribute__((ext_vector_type(8)));
typedef float floatx4 __attribute__((ext_vector_type(4)));

#define NB_V 30000

__device__ __forceinline__ unsigned short f32_bf16(float f) {
  union { float f; uint32_t u; } v; v.f = f;
  return (unsigned short)((v.u + 0x7FFFu + ((v.u >> 16) & 1u)) >> 16);
}
__device__ __forceinline__ float bf16_f32(unsigned short h) {
  union { uint32_t u; float f; } v; v.u = ((uint32_t)h) << 16;
  return v.f;
}

// ---------------- wv -> bf16, padded to 30080 x 320 ----------------
__global__ __launch_bounds__(256) void k_convert(const float* __restrict__ wv,
                                                 unsigned short* __restrict__ wv_bf) {
  int t = blockIdx.x * 256 + threadIdx.x;
  if (t >= 30080 * 40) return;
  int row = t / 40, kc = (t % 40) * 8;
  ushort8 o;
  if (row < NB_V && kc + 8 <= 300) {
    const float* p = wv + (size_t)row * 300 + kc;
    float4 a = *(const float4*)p, b = *(const float4*)(p + 4);
    o[0] = f32_bf16(a.x); o[1] = f32_bf16(a.y); o[2] = f32_bf16(a.z); o[3] = f32_bf16(a.w);
    o[4] = f32_bf16(b.x); o[5] = f32_bf16(b.y); o[6] = f32_bf16(b.z); o[7] = f32_bf16(b.w);
  } else if (row < NB_V) {
#pragma unroll
    for (int e = 0; e < 8; e++)
      o[e] = (kc + e < 300) ? f32_bf16(wv[(size_t)row * 300 + kc + e]) : (unsigned short)0;
  } else {
#pragma unroll
    for (int e = 0; e < 8; e++) o[e] = 0;
  }
  *(ushort8*)(wv_bf + (size_t)row * 320 + kc) = o;
}

// ---------------- Stage A: vocab projection GEMM ----------------
// grid = 235 Mblocks x 12 Nblocks; block 256 (4 waves). 128x64 tile, K=320.
__global__ __launch_bounds__(256) void k_project(
    const unsigned short* __restrict__ wv_bf,
    const float* __restrict__ Wu, const float* __restrict__ Wb,
    const float* __restrict__ Wt,
    unsigned short* __restrict__ P) {
  __shared__ __align__(16) unsigned short wlds[64 * 328];  // stride 328
  int tid = threadIdx.x;
  int bid = blockIdx.x;
  int mb = bid / 12, nb = bid % 12;
  int seg = nb >> 1, h = nb & 1;
  const float* Wsrc; int kw, jj;
  if (seg == 0)       { Wsrc = Wu; kw = 1; jj = 0; }
  else if (seg <= 2)  { Wsrc = Wb; kw = 2; jj = seg - 1; }
  else                { Wsrc = Wt; kw = 3; jj = seg - 3; }
  {
    int cl = tid >> 2;                 // 0..63 local col
    int k0 = (tid & 3) * 80;
    const float* srow = Wsrc + ((size_t)(h * 64 + cl) * kw + jj) * 300;
    unsigned short* drow = &wlds[cl * 328];
    for (int i = 0; i < 20; i++) {
      int k = k0 + i * 4;
      float x0 = 0.f, x1 = 0.f, x2 = 0.f, x3 = 0.f;
      if (k + 4 <= 300) {
        float4 f = *(const float4*)(srow + k);
        x0 = f.x; x1 = f.y; x2 = f.z; x3 = f.w;
      }
      drow[k + 0] = f32_bf16(x0); drow[k + 1] = f32_bf16(x1);
      drow[k + 2] = f32_bf16(x2); drow[k + 3] = f32_bf16(x3);
    }
  }
  __syncthreads();

  int wave = tid >> 6, lane = tid & 63;
  int li = lane & 15, quad = lane >> 4;
  int rows0 = mb * 128 + wave * 32;
  floatx4 acc[2][4];
#pragma unroll
  for (int rt = 0; rt < 2; rt++)
#pragma unroll
    for (int ct = 0; ct < 4; ct++) acc[rt][ct] = (floatx4){0.f, 0.f, 0.f, 0.f};

  const unsigned short* abase = wv_bf + (size_t)(rows0 + li) * 320;
#pragma unroll 2
  for (int ks = 0; ks < 10; ks++) {
    int ck = ks * 32 + quad * 8;
    short8 a0 = *(const short8*)(abase + ck);
    short8 a1 = *(const short8*)(abase + 16 * 320 + ck);
#pragma unroll
    for (int ct = 0; ct < 4; ct++) {
      short8 bf = *(const short8*)&wlds[(ct * 16 + li) * 328 + ck];
      acc[0][ct] = __builtin_amdgcn_mfma_f32_16x16x32_bf16(a0, bf, acc[0][ct], 0, 0, 0);
      acc[1][ct] = __builtin_amdgcn_mfma_f32_16x16x32_bf16(a1, bf, acc[1][ct], 0, 0, 0);
    }
  }
#pragma unroll
  for (int rt = 0; rt < 2; rt++)
#pragma unroll
    for (int ct = 0; ct < 4; ct++)
#pragma unroll
      for (int r = 0; r < 4; r++) {
        int row = rows0 + rt * 16 + quad * 4 + r;   // < 30080, P padded
        P[(size_t)row * 768 + nb * 64 + ct * 16 + li] = f32_bf16(acc[rt][ct][r]);
      }
}

// ---------------- Stage B: build normalized n-gram vectors ----------------
__device__ __forceinline__ void build_vec(
    int b, int type, int l, int L,
    const int* __restrict__ tokens, const unsigned short* __restrict__ P,
    const float* __restrict__ bias,
    unsigned short* __restrict__ vec, float* __restrict__ inv, int lane) {
  const int segBase[3] = {0, 128, 384};
  size_t row = (size_t)(b * 3 + type) * L + l;
  uint32_t* vout = (uint32_t*)(vec + row * 128);
  int kk = type + 1;
  if (l + kk <= L) {
    const int* tk = tokens + (size_t)b * L + l;
    float v0 = bias[2 * lane], v1 = bias[2 * lane + 1];
    for (int j = 0; j < kk; j++) {
      uint32_t pp = *(const uint32_t*)(P + (size_t)tk[j] * 768 + segBase[type] + j * 128 + 2 * lane);
      v0 += bf16_f32((unsigned short)(pp & 0xFFFFu));
      v1 += bf16_f32((unsigned short)(pp >> 16));
    }
    v0 = fmaxf(v0, 0.0f) + 1e-9f;
    v1 = fmaxf(v1, 0.0f) + 1e-9f;
    float ss = v0 * v0 + v1 * v1;
#pragma unroll
    for (int o = 1; o < 64; o <<= 1) ss += __shfl_xor(ss, o);
    float rn = 1.0f / sqrtf(ss);
    unsigned short r0 = f32_bf16(v0 * rn), r1 = f32_bf16(v1 * rn);
    float f0 = bf16_f32(r0), f1 = bf16_f32(r1);
    float s2 = f0 * f0 + f1 * f1;
#pragma unroll
    for (int o = 1; o < 64; o <<= 1) s2 += __shfl_xor(s2, o);
    vout[lane] = (uint32_t)r0 | ((uint32_t)r1 << 16);
    if (lane == 0) inv[row] = rsqrtf(s2);   // 1/||bf16 vec||: exact-match sims -> 1.0
  } else {
    vout[lane] = 0u;
    if (lane == 0) inv[row] = 0.0f;
  }
}

// one wave per (b, type, position) -> max TLP, no serial position loop
__global__ __launch_bounds__(256) void k_vectors(
    const int* __restrict__ qtok, const int* __restrict__ dtok,
    const unsigned short* __restrict__ P,
    const float* __restrict__ bu, const float* __restrict__ bb,
    const float* __restrict__ bt,
    unsigned short* __restrict__ dvec, float* __restrict__ dinv,
    unsigned short* __restrict__ qvec, float* __restrict__ qinv) {
  int wid = blockIdx.x * 4 + (threadIdx.x >> 6);
  int lane = threadIdx.x & 63;
  const int NDOC = 32 * 3 * 4096;  // 393216 doc waves
  if (wid < NDOC) {
    int b = wid / 12288;
    int rem = wid % 12288;
    int type = rem / 4096, l = rem & 4095;
    const float* bias = (type == 0) ? bu : (type == 1) ? bb : bt;
    build_vec(b, type, l, 4096, dtok, P, bias, dvec, dinv, lane);
  } else {
    int t2 = wid - NDOC;
    if (t2 < 32 * 48) {
      int b = t2 / 48;
      int rem = t2 % 48;
      int type = rem >> 4, l = rem & 15;
      const float* bias = (type == 0) ? bu : (type == 1) ? bb : bt;
      build_vec(b, type, l, 16, qtok, P, bias, qvec, qinv, lane);
    }
  }
}

// ---------------- Stage C: fused sim + Gaussian kernel pooling ----------------
// grid = 32 b * 3 dt * 16 chunks (256 docs). block 256 = 4 waves. NO atomics:
// per-block partial[bid][3qt][16q][11] via shfl + LDS cross-wave reduce.
__global__ __launch_bounds__(256) void k_pool(
    const unsigned short* __restrict__ dvec, const float* __restrict__ dinv,
    const unsigned short* __restrict__ qvec, const float* __restrict__ qinv,
    float* __restrict__ partial) {
  constexpr float MU[11] = {1.f, .9f, .7f, .5f, .3f, .1f, -.1f, -.3f, -.5f, -.7f, -.9f};
  constexpr float CF[11] = {-500000.f, -50.f, -50.f, -50.f, -50.f, -50.f,
                            -50.f, -50.f, -50.f, -50.f, -50.f};
  __shared__ __align__(16) unsigned short qlds[48 * 136];
  __shared__ float qil[48];
  __shared__ float pacc[4 * 528];
  int bid = blockIdx.x;
  int b = bid / 48, rem = bid % 48;
  int dt = rem / 16, chunk = rem % 16;
  int tid = threadIdx.x;
  for (int idx = tid; idx < 48 * 32; idx += 256) {
    int row = idx >> 5, kq = (idx & 31) * 4;
    *(uint2*)&qlds[row * 136 + kq] =
        *(const uint2*)(qvec + ((size_t)b * 48 + row) * 128 + kq);
  }
  if (tid < 48) qil[tid] = qinv[b * 48 + tid];
  __syncthreads();

  int wave = tid >> 6, lane = tid & 63;
  int li = lane & 15, quad = lane >> 4;
  int validD = 4096 - dt;
  const unsigned short* dbp = dvec + ((size_t)b * 3 + dt) * 4096 * 128;
  const float* dip = dinv + ((size_t)b * 3 + dt) * 4096;

  float accb[3][11];
#pragma unroll
  for (int qt = 0; qt < 3; qt++)
#pragma unroll
    for (int i = 0; i < 11; i++) accb[qt][i] = 0.f;

  for (int blk = wave; blk < 16; blk += 4) {
    int db = chunk * 256 + blk * 16;
    const short8* ap = (const short8*)(dbp + (size_t)(db + li) * 128 + quad * 8);
    short8 af0 = ap[0], af1 = ap[4], af2 = ap[8], af3 = ap[12];
    float4 iv4 = *(const float4*)(dip + db + quad * 4);
    float iv[4] = {iv4.x, iv4.y, iv4.z, iv4.w};
#pragma unroll
    for (int qt = 0; qt < 3; qt++) {
      floatx4 sim = (floatx4){0.f, 0.f, 0.f, 0.f};
      const unsigned short* qb = &qlds[(qt * 16 + li) * 136 + quad * 8];
      sim = __builtin_amdgcn_mfma_f32_16x16x32_bf16(af0, *(const short8*)(qb), sim, 0, 0, 0);
      sim = __builtin_amdgcn_mfma_f32_16x16x32_bf16(af1, *(const short8*)(qb + 32), sim, 0, 0, 0);
      sim = __builtin_amdgcn_mfma_f32_16x16x32_bf16(af2, *(const short8*)(qb + 64), sim, 0, 0, 0);
      sim = __builtin_amdgcn_mfma_f32_16x16x32_bf16(af3, *(const short8*)(qb + 96), sim, 0, 0, 0);
      float invq = qil[qt * 16 + li];
#pragma unroll
      for (int r = 0; r < 4; r++) {
        if (db + quad * 4 + r < validD) {
          float s = sim[r] * (invq * iv[r]);
#pragma unroll
          for (int i = 0; i < 11; i++) {
            float t = s - MU[i];
            accb[qt][i] += __expf(t * t * CF[i]);
          }
        }
      }
    }
  }
  // wave-level quad reduce, then LDS store (lane == q row)
#pragma unroll
  for (int qt = 0; qt < 3; qt++) {
#pragma unroll
    for (int i = 0; i < 11; i++) {
      float v = accb[qt][i];
      v += __shfl_xor(v, 16);
      v += __shfl_xor(v, 32);
      if (lane < 16) pacc[wave * 528 + (qt * 16 + lane) * 11 + i] = v;
    }
  }
  __syncthreads();
  float* pout = partial + (size_t)bid * 528;
  for (int idx = tid; idx < 528; idx += 256)
    pout[idx] = pacc[idx] + pacc[528 + idx] + pacc[1056 + idx] + pacc[1584 + idx];
}

// ---------------- chunk reduction: partial -> gacc ----------------
__global__ __launch_bounds__(256) void k_reduce(const float* __restrict__ partial,
                                                float* __restrict__ gacc) {
  int idx = blockIdx.x * 256 + threadIdx.x;
  if (idx >= 32 * 3 * 16 * 3 * 11) return;
  int i = idx % 11; int t = idx / 11;
  int dt = t % 3; t /= 3;
  int q = t % 16; t /= 16;
  int qt = t % 3; int b = t / 3;
  const float* p = partial + (((size_t)(b * 3 + dt) * 16) * 528) + (qt * 16 + q) * 11 + i;
  float s = 0.f;
#pragma unroll
  for (int c = 0; c < 16; c++) s += p[c * 528];
  gacc[(((size_t)b * 3 + qt) * 16 + q) * 33 + dt * 11 + i] = s;
}

// ---------------- Stage D: log / clip / query-sum epilogue ----------------
__global__ void k_final(const float* __restrict__ gacc, float* __restrict__ out) {
  int idx = blockIdx.x * 256 + threadIdx.x;
  if (idx >= 32 * 99) return;
  int b = idx / 99, r = idx % 99;
  int p = r / 11, bin = r % 11;
  const int qt_of[9] = {0, 0, 0, 1, 2, 1, 1, 2, 2};
  const int dt_of[9] = {0, 2, 1, 0, 0, 1, 2, 1, 2};
  int qt = qt_of[p], dt = dt_of[p];
  float s = 0.f;
  for (int q = 0; q < 16 - qt; q++) {
    float v = gacc[((b * 3 + qt) * 16 + q) * 33 + dt * 11 + bin];
    s += 0.01f * logf(fmaxf(v, 1e-10f));
  }
  out[idx] = s;
}

extern "C" void kernel_launch(void* const* d_in, const int* in_sizes, int n_in,
                              void* d_out, int out_size, void* d_ws, size_t ws_size,
                              hipStream_t stream) {
  const int* qtok = (const int*)d_in[0];
  const int* dtok = (const int*)d_in[1];
  // d_in[2] = batch_semantic: unused by the reference
  const float* wv = (const float*)d_in[3];
  const float* Wu = (const float*)d_in[4];
  const float* bu = (const float*)d_in[5];
  const float* Wb = (const float*)d_in[6];
  const float* bb = (const float*)d_in[7];
  const float* Wt = (const float*)d_in[8];
  const float* bt = (const float*)d_in[9];
  float* out = (float*)d_out;

  // workspace layout (bytes), footprint 148,838,400:
  //   P:      [0, 46,202,880)            30080*768*2  (dead after k_vectors)
  //   dvec:   [46,202,880, 146,866,176)  32*3*4096*128*2
  //     wv_bf aliases dvec base: 30080*320*2 = 19,251,200 (dead after k_project)
  //   dinv:   [146,866,176, 148,439,040)
  //   qvec:   [148,439,040, 148,832,256)
  //   qinv:   [148,832,256, 148,838,400)
  //   partial aliases P base: 1536*528*4 = 3,244,032
  //   gacc    aliases P+4,194,304: 50688*4 = 202,752
  char* ws = (char*)d_ws;
  unsigned short* P     = (unsigned short*)(ws);
  unsigned short* wv_bf = (unsigned short*)(ws + 46202880);
  unsigned short* dvec  = (unsigned short*)(ws + 46202880);
  float* dinv           = (float*)(ws + 146866176);
  unsigned short* qvec  = (unsigned short*)(ws + 148439040);
  float* qinv           = (float*)(ws + 148832256);
  float* partial        = (float*)(ws);
  float* gacc           = (float*)(ws + 4194304);

  k_convert<<<4700, 256, 0, stream>>>(wv, wv_bf);
  k_project<<<235 * 12, 256, 0, stream>>>(wv_bf, Wu, Wb, Wt, P);
  k_vectors<<<98688, 256, 0, stream>>>(qtok, dtok, P, bu, bb, bt, dvec, dinv, qvec, qinv);
  k_pool<<<32 * 3 * 16, 256, 0, stream>>>(dvec, dinv, qvec, qinv, partial);
  k_reduce<<<198, 256, 0, stream>>>(partial, gacc);
  k_final<<<13, 256, 0, stream>>>(gacc, out);
}

// Round 3
// 249.158 us; speedup vs baseline: 2.1598x; 1.3334x over previous
//
#include <hip/hip_runtime.h>
#include <stdint.h>

// CONV-KNRM fused pipeline for MI355X (gfx950). Round 3:
//  - k_vectors: 4 vectors/wave (16 lanes x 8 elem), UN-normalized bf16 store
//    + inv = rsqrt(sum r^2)  -> one width-16 reduction, no normalize round-trip.
//  - k_project: both 64-col halves of a segment per block, A frags cached in
//    registers across halves (A global traffic halved).
// B=32, Q=16, D=4096, V=30000, C=128, EM=300, NBINS=11.

typedef short short8 __attribute__((ext_vector_type(8)));
typedef unsigned short ushort8 __attribute__((ext_vector_type(8)));
typedef float floatx4 __attribute__((ext_vector_type(4)));

#define NB_V 30000

__device__ __forceinline__ unsigned short f32_bf16(float f) {
  union { float f; uint32_t u; } v; v.f = f;
  return (unsigned short)((v.u + 0x7FFFu + ((v.u >> 16) & 1u)) >> 16);
}
__device__ __forceinline__ float bf16_f32(unsigned short h) {
  union { uint32_t u; float f; } v; v.u = ((uint32_t)h) << 16;
  return v.f;
}
// rounded bf16 of f, returned as the f32 bit-pattern (bf16 in high half)
__device__ __forceinline__ uint32_t rnd_hi(float f) {
  union { float f; uint32_t u; } v; v.f = f;
  return (v.u + 0x7FFFu + ((v.u >> 16) & 1u)) & 0xFFFF0000u;
}
__device__ __forceinline__ float bits_f32(uint32_t u) {
  union { uint32_t u; float f; } v; v.u = u; return v.f;
}
__device__ __forceinline__ float bflo(uint32_t u) { return bits_f32(u << 16); }
__device__ __forceinline__ float bfhi(uint32_t u) { return bits_f32(u & 0xFFFF0000u); }

// ---------------- wv -> bf16, padded to 30080 x 320 ----------------
__global__ __launch_bounds__(256) void k_convert(const float* __restrict__ wv,
                                                 unsigned short* __restrict__ wv_bf) {
  int t = blockIdx.x * 256 + threadIdx.x;
  if (t >= 30080 * 40) return;
  int row = t / 40, kc = (t % 40) * 8;
  ushort8 o;
  if (row < NB_V && kc + 8 <= 300) {
    const float* p = wv + (size_t)row * 300 + kc;
    float4 a = *(const float4*)p, b = *(const float4*)(p + 4);
    o[0] = f32_bf16(a.x); o[1] = f32_bf16(a.y); o[2] = f32_bf16(a.z); o[3] = f32_bf16(a.w);
    o[4] = f32_bf16(b.x); o[5] = f32_bf16(b.y); o[6] = f32_bf16(b.z); o[7] = f32_bf16(b.w);
  } else if (row < NB_V) {
#pragma unroll
    for (int e = 0; e < 8; e++)
      o[e] = (kc + e < 300) ? f32_bf16(wv[(size_t)row * 300 + kc + e]) : (unsigned short)0;
  } else {
#pragma unroll
    for (int e = 0; e < 8; e++) o[e] = 0;
  }
  *(ushort8*)(wv_bf + (size_t)row * 320 + kc) = o;
}

// ---------------- Stage A: vocab projection GEMM ----------------
// grid = 235 Mblocks x 6 segments; block 256 (4 waves). 128 rows x 128 cols,
// K=320. A fragments register-cached across the two 64-col halves.
__global__ __launch_bounds__(256) void k_project(
    const unsigned short* __restrict__ wv_bf,
    const float* __restrict__ Wu, const float* __restrict__ Wb,
    const float* __restrict__ Wt,
    unsigned short* __restrict__ P) {
  __shared__ __align__(16) unsigned short wlds[64 * 328];
  int tid = threadIdx.x;
  int bid = blockIdx.x;
  int mb = bid / 6, seg = bid % 6;
  const float* Wsrc; int kw, jj;
  if (seg == 0)       { Wsrc = Wu; kw = 1; jj = 0; }
  else if (seg <= 2)  { Wsrc = Wb; kw = 2; jj = seg - 1; }
  else                { Wsrc = Wt; kw = 3; jj = seg - 3; }

  int wave = tid >> 6, lane = tid & 63;
  int li = lane & 15, quad = lane >> 4;
  int rows0 = mb * 128 + wave * 32;

  // A fragments for both 16-row tiles, all 10 K-steps (80 VGPRs)
  short8 af[2][10];
  const unsigned short* abase = wv_bf + (size_t)(rows0 + li) * 320 + quad * 8;
#pragma unroll
  for (int ks = 0; ks < 10; ks++) {
    af[0][ks] = *(const short8*)(abase + ks * 32);
    af[1][ks] = *(const short8*)(abase + 16 * 320 + ks * 32);
  }

  for (int h = 0; h < 2; h++) {
    {  // stage W(h) into LDS (64 channels x 320 K, bf16, stride 328)
      int cl = tid >> 2;
      int k0 = (tid & 3) * 80;
      const float* srow = Wsrc + ((size_t)(h * 64 + cl) * kw + jj) * 300;
      unsigned short* drow = &wlds[cl * 328];
      for (int i = 0; i < 20; i++) {
        int k = k0 + i * 4;
        float x0 = 0.f, x1 = 0.f, x2 = 0.f, x3 = 0.f;
        if (k + 4 <= 300) {
          float4 f = *(const float4*)(srow + k);
          x0 = f.x; x1 = f.y; x2 = f.z; x3 = f.w;
        }
        drow[k + 0] = f32_bf16(x0); drow[k + 1] = f32_bf16(x1);
        drow[k + 2] = f32_bf16(x2); drow[k + 3] = f32_bf16(x3);
      }
    }
    __syncthreads();

    floatx4 acc[2][4];
#pragma unroll
    for (int rt = 0; rt < 2; rt++)
#pragma unroll
      for (int ct = 0; ct < 4; ct++) acc[rt][ct] = (floatx4){0.f, 0.f, 0.f, 0.f};

#pragma unroll
    for (int ks = 0; ks < 10; ks++) {
      int ck = ks * 32 + quad * 8;
#pragma unroll
      for (int ct = 0; ct < 4; ct++) {
        short8 bf = *(const short8*)&wlds[(ct * 16 + li) * 328 + ck];
        acc[0][ct] = __builtin_amdgcn_mfma_f32_16x16x32_bf16(af[0][ks], bf, acc[0][ct], 0, 0, 0);
        acc[1][ct] = __builtin_amdgcn_mfma_f32_16x16x32_bf16(af[1][ks], bf, acc[1][ct], 0, 0, 0);
      }
    }
#pragma unroll
    for (int rt = 0; rt < 2; rt++)
#pragma unroll
      for (int ct = 0; ct < 4; ct++)
#pragma unroll
        for (int r = 0; r < 4; r++) {
          int row = rows0 + rt * 16 + quad * 4 + r;   // < 30080, P padded
          P[(size_t)row * 768 + seg * 128 + h * 64 + ct * 16 + li] =
              f32_bf16(acc[rt][ct][r]);
        }
    __syncthreads();   // LDS safe to restage
  }
}

// ---------------- Stage B: build n-gram vectors (4 per wave) ----------------
// 16 lanes per vector, 8 elements per lane. Stores UN-normalized bf16 r and
// inv = rsqrt(sum r^2); exact n-gram matches give identical bytes -> sim == 1.
template <int KK>
__device__ __forceinline__ void build_vec4(
    int b, int type, int l0, int L,
    const int* __restrict__ tokens, const unsigned short* __restrict__ P,
    const float* __restrict__ bias,
    unsigned short* __restrict__ vec, float* __restrict__ inv, int lane) {
  const int segBase[3] = {0, 128, 384};
  int sub = lane >> 4, li = lane & 15;
  int l = l0 + sub;
  size_t row = (size_t)(b * 3 + type) * L + l;
  uint4 o = make_uint4(0u, 0u, 0u, 0u);
  float invv = 0.0f;
  if (l + KK <= L) {
    float v[8];
    {
      float4 b0 = *(const float4*)(bias + li * 8);
      float4 b1 = *(const float4*)(bias + li * 8 + 4);
      v[0] = b0.x; v[1] = b0.y; v[2] = b0.z; v[3] = b0.w;
      v[4] = b1.x; v[5] = b1.y; v[6] = b1.z; v[7] = b1.w;
    }
    const int* tk = tokens + (size_t)b * L + l;
    const unsigned short* pb = P + segBase[type] + li * 8;
#pragma unroll
    for (int j = 0; j < KK; j++) {
      uint4 pp = *(const uint4*)(pb + (size_t)tk[j] * 768 + j * 128);
      v[0] += bflo(pp.x); v[1] += bfhi(pp.x);
      v[2] += bflo(pp.y); v[3] += bfhi(pp.y);
      v[4] += bflo(pp.z); v[5] += bfhi(pp.z);
      v[6] += bflo(pp.w); v[7] += bfhi(pp.w);
    }
    uint32_t w[4];
    float s = 0.0f;
#pragma unroll
    for (int e = 0; e < 4; e++) {
      float f0 = fmaxf(v[2 * e], 0.0f) + 1e-9f;
      float f1 = fmaxf(v[2 * e + 1], 0.0f) + 1e-9f;
      uint32_t h0 = rnd_hi(f0), h1 = rnd_hi(f1);
      w[e] = (h0 >> 16) | h1;
      float g0 = bits_f32(h0), g1 = bits_f32(h1);
      s = fmaf(g0, g0, fmaf(g1, g1, s));
    }
#pragma unroll
    for (int off = 1; off < 16; off <<= 1) s += __shfl_xor(s, off);
    invv = rsqrtf(s);
    o = make_uint4(w[0], w[1], w[2], w[3]);
  }
  *(uint4*)(vec + row * 128 + li * 8) = o;
  if (li == 0) inv[row] = invv;
}

__device__ __forceinline__ void build_vec4_dispatch(
    int b, int type, int l0, int L,
    const int* __restrict__ tokens, const unsigned short* __restrict__ P,
    const float* __restrict__ bu, const float* __restrict__ bb,
    const float* __restrict__ bt,
    unsigned short* __restrict__ vec, float* __restrict__ inv, int lane) {
  if (type == 0)      build_vec4<1>(b, 0, l0, L, tokens, P, bu, vec, inv, lane);
  else if (type == 1) build_vec4<2>(b, 1, l0, L, tokens, P, bb, vec, inv, lane);
  else                build_vec4<3>(b, 2, l0, L, tokens, P, bt, vec, inv, lane);
}

__global__ __launch_bounds__(256) void k_vectors(
    const int* __restrict__ qtok, const int* __restrict__ dtok,
    const unsigned short* __restrict__ P,
    const float* __restrict__ bu, const float* __restrict__ bb,
    const float* __restrict__ bt,
    unsigned short* __restrict__ dvec, float* __restrict__ dinv,
    unsigned short* __restrict__ qvec, float* __restrict__ qinv) {
  int wid = blockIdx.x * 4 + (threadIdx.x >> 6);
  int lane = threadIdx.x & 63;
  const int NDOCW = 32 * 3 * 1024;  // doc waves (4 positions each)
  if (wid < NDOCW) {
    int b = wid / 3072;
    int rem = wid % 3072;
    int type = rem / 1024, l0 = (rem % 1024) * 4;
    build_vec4_dispatch(b, type, l0, 4096, dtok, P, bu, bb, bt, dvec, dinv, lane);
  } else {
    int t2 = wid - NDOCW;  // 384 query waves
    int b = t2 / 12;
    int rem = t2 % 12;
    int type = rem / 4, l0 = (rem % 4) * 4;
    build_vec4_dispatch(b, type, l0, 16, qtok, P, bu, bb, bt, qvec, qinv, lane);
  }
}

// ---------------- Stage C: fused sim + Gaussian kernel pooling ----------------
__global__ __launch_bounds__(256) void k_pool(
    const unsigned short* __restrict__ dvec, const float* __restrict__ dinv,
    const unsigned short* __restrict__ qvec, const float* __restrict__ qinv,
    float* __restrict__ partial) {
  constexpr float MU[11] = {1.f, .9f, .7f, .5f, .3f, .1f, -.1f, -.3f, -.5f, -.7f, -.9f};
  constexpr float CF[11] = {-500000.f, -50.f, -50.f, -50.f, -50.f, -50.f,
                            -50.f, -50.f, -50.f, -50.f, -50.f};
  __shared__ __align__(16) unsigned short qlds[48 * 136];
  __shared__ float qil[48];
  __shared__ float pacc[4 * 528];
  int bid = blockIdx.x;
  int b = bid / 48, rem = bid % 48;
  int dt = rem / 16, chunk = rem % 16;
  int tid = threadIdx.x;
  for (int idx = tid; idx < 48 * 32; idx += 256) {
    int row = idx >> 5, kq = (idx & 31) * 4;
    *(uint2*)&qlds[row * 136 + kq] =
        *(const uint2*)(qvec + ((size_t)b * 48 + row) * 128 + kq);
  }
  if (tid < 48) qil[tid] = qinv[b * 48 + tid];
  __syncthreads();

  int wave = tid >> 6, lane = tid & 63;
  int li = lane & 15, quad = lane >> 4;
  int validD = 4096 - dt;
  const unsigned short* dbp = dvec + ((size_t)b * 3 + dt) * 4096 * 128;
  const float* dip = dinv + ((size_t)b * 3 + dt) * 4096;

  float accb[3][11];
#pragma unroll
  for (int qt = 0; qt < 3; qt++)
#pragma unroll
    for (int i = 0; i < 11; i++) accb[qt][i] = 0.f;

  for (int blk = wave; blk < 16; blk += 4) {
    int db = chunk * 256 + blk * 16;
    const short8* ap = (const short8*)(dbp + (size_t)(db + li) * 128 + quad * 8);
    short8 af0 = ap[0], af1 = ap[4], af2 = ap[8], af3 = ap[12];
    float4 iv4 = *(const float4*)(dip + db + quad * 4);
    float iv[4] = {iv4.x, iv4.y, iv4.z, iv4.w};
#pragma unroll
    for (int qt = 0; qt < 3; qt++) {
      floatx4 sim = (floatx4){0.f, 0.f, 0.f, 0.f};
      const unsigned short* qb = &qlds[(qt * 16 + li) * 136 + quad * 8];
      sim = __builtin_amdgcn_mfma_f32_16x16x32_bf16(af0, *(const short8*)(qb), sim, 0, 0, 0);
      sim = __builtin_amdgcn_mfma_f32_16x16x32_bf16(af1, *(const short8*)(qb + 32), sim, 0, 0, 0);
      sim = __builtin_amdgcn_mfma_f32_16x16x32_bf16(af2, *(const short8*)(qb + 64), sim, 0, 0, 0);
      sim = __builtin_amdgcn_mfma_f32_16x16x32_bf16(af3, *(const short8*)(qb + 96), sim, 0, 0, 0);
      float invq = qil[qt * 16 + li];
#pragma unroll
      for (int r = 0; r < 4; r++) {
        if (db + quad * 4 + r < validD) {
          float s = sim[r] * (invq * iv[r]);
#pragma unroll
          for (int i = 0; i < 11; i++) {
            float t = s - MU[i];
            accb[qt][i] += __expf(t * t * CF[i]);
          }
        }
      }
    }
  }
#pragma unroll
  for (int qt = 0; qt < 3; qt++) {
#pragma unroll
    for (int i = 0; i < 11; i++) {
      float v = accb[qt][i];
      v += __shfl_xor(v, 16);
      v += __shfl_xor(v, 32);
      if (lane < 16) pacc[wave * 528 + (qt * 16 + lane) * 11 + i] = v;
    }
  }
  __syncthreads();
  float* pout = partial + (size_t)bid * 528;
  for (int idx = tid; idx < 528; idx += 256)
    pout[idx] = pacc[idx] + pacc[528 + idx] + pacc[1056 + idx] + pacc[1584 + idx];
}

// ---------------- chunk reduction: partial -> gacc ----------------
__global__ __launch_bounds__(256) void k_reduce(const float* __restrict__ partial,
                                                float* __restrict__ gacc) {
  int idx = blockIdx.x * 256 + threadIdx.x;
  if (idx >= 32 * 3 * 16 * 3 * 11) return;
  int i = idx % 11; int t = idx / 11;
  int dt = t % 3; t /= 3;
  int q = t % 16; t /= 16;
  int qt = t % 3; int b = t / 3;
  const float* p = partial + (((size_t)(b * 3 + dt) * 16) * 528) + (qt * 16 + q) * 11 + i;
  float s = 0.f;
#pragma unroll
  for (int c = 0; c < 16; c++) s += p[c * 528];
  gacc[(((size_t)b * 3 + qt) * 16 + q) * 33 + dt * 11 + i] = s;
}

// ---------------- Stage D: log / clip / query-sum epilogue ----------------
__global__ void k_final(const float* __restrict__ gacc, float* __restrict__ out) {
  int idx = blockIdx.x * 256 + threadIdx.x;
  if (idx >= 32 * 99) return;
  int b = idx / 99, r = idx % 99;
  int p = r / 11, bin = r % 11;
  const int qt_of[9] = {0, 0, 0, 1, 2, 1, 1, 2, 2};
  const int dt_of[9] = {0, 2, 1, 0, 0, 1, 2, 1, 2};
  int qt = qt_of[p], dt = dt_of[p];
  float s = 0.f;
  for (int q = 0; q < 16 - qt; q++) {
    float v = gacc[((b * 3 + qt) * 16 + q) * 33 + dt * 11 + bin];
    s += 0.01f * logf(fmaxf(v, 1e-10f));
  }
  out[idx] = s;
}

extern "C" void kernel_launch(void* const* d_in, const int* in_sizes, int n_in,
                              void* d_out, int out_size, void* d_ws, size_t ws_size,
                              hipStream_t stream) {
  const int* qtok = (const int*)d_in[0];
  const int* dtok = (const int*)d_in[1];
  // d_in[2] = batch_semantic: unused by the reference
  const float* wv = (const float*)d_in[3];
  const float* Wu = (const float*)d_in[4];
  const float* bu = (const float*)d_in[5];
  const float* Wb = (const float*)d_in[6];
  const float* bb = (const float*)d_in[7];
  const float* Wt = (const float*)d_in[8];
  const float* bt = (const float*)d_in[9];
  float* out = (float*)d_out;

  // workspace layout (bytes), footprint 148,838,400:
  //   P:      [0, 46,202,880)            30080*768*2  (dead after k_vectors)
  //   dvec:   [46,202,880, 146,866,176)  32*3*4096*128*2
  //     wv_bf aliases dvec base: 30080*320*2 = 19,251,200 (dead after k_project)
  //   dinv:   [146,866,176, 148,439,040)
  //   qvec:   [148,439,040, 148,832,256)
  //   qinv:   [148,832,256, 148,838,400)
  //   partial aliases P base: 1536*528*4 = 3,244,032
  //   gacc    aliases P+4,194,304: 50688*4 = 202,752
  char* ws = (char*)d_ws;
  unsigned short* P     = (unsigned short*)(ws);
  unsigned short* wv_bf = (unsigned short*)(ws + 46202880);
  unsigned short* dvec  = (unsigned short*)(ws + 46202880);
  float* dinv           = (float*)(ws + 146866176);
  unsigned short* qvec  = (unsigned short*)(ws + 148439040);
  float* qinv           = (float*)(ws + 148832256);
  float* partial        = (float*)(ws);
  float* gacc           = (float*)(ws + 4194304);

  k_convert<<<4700, 256, 0, stream>>>(wv, wv_bf);
  k_project<<<235 * 6, 256, 0, stream>>>(wv_bf, Wu, Wb, Wt, P);
  k_vectors<<<24672, 256, 0, stream>>>(qtok, dtok, P, bu, bb, bt, dvec, dinv, qvec, qinv);
  k_pool<<<32 * 3 * 16, 256, 0, stream>>>(dvec, dinv, qvec, qinv, partial);
  k_reduce<<<198, 256, 0, stream>>>(partial, gacc);
  k_final<<<13, 256, 0, stream>>>(gacc, out);
}